// Round 4
// baseline (947.703 us; speedup 1.0000x reference)
//
#include <hip/hip_runtime.h>

#define CH    768
#define BC    96
#define WWW   128
#define WF    65
#define LAMBD_ 0.01f
#define NPOS  33280              // B*H*WF = 4*128*65
#define SOFF  204472320ull       // bytes of spectrum S in d_ws
#define LDST  100                // padded f32 row stride for LDS planes (100%32=4)

typedef __bf16 bf16x8 __attribute__((ext_vector_type(8)));
typedef float  f32x4  __attribute__((ext_vector_type(4)));
typedef unsigned short ushort_t;

union U8 { ushort_t u[8]; bf16x8 v; uint4 q; };

__device__ __forceinline__ ushort_t rnbf(float f) {   // f32 -> bf16 round-to-nearest-even
  unsigned u = __builtin_bit_cast(unsigned, f);
  return (ushort_t)((u + 0x7FFFu + ((u >> 16) & 1u)) >> 16);
}

// ---------- compile-time twiddle table: c[k]=cos(2*pi*k/128), s[k]=sin(2*pi*k/128)
struct Tab {
  float c[64]; float s[64];
  static constexpr double tsin(double x) {
    double t = x, r = x; const double x2 = x * x;
    for (int i = 1; i <= 15; ++i) { t *= -x2 / ((2.0 * i) * (2.0 * i + 1.0)); r += t; }
    return r;
  }
  static constexpr double tcos(double x) {
    double t = 1.0, r = 1.0; const double x2 = x * x;
    for (int i = 1; i <= 15; ++i) { t *= -x2 / ((2.0 * i - 1.0) * (2.0 * i)); r += t; }
    return r;
  }
  constexpr Tab() : c{}, s{} {
    for (int k = 0; k < 64; ++k) {
      const double a = 6.283185307179586476925287 * (double)k / 128.0;
      c[k] = (float)tcos(a); s[k] = (float)tsin(a);
    }
  }
};
__device__ const Tab DTAB{};

__host__ __device__ constexpr int rev6(int n) {
  int r = 0;
  for (int b = 0; b < 6; ++b) r |= ((n >> b) & 1) << (5 - b);
  return r;
}

// ---------- fully-unrolled in-place DIT FFT-64 on registers
template<bool INV>
__device__ __forceinline__ void fft64_reg(float (&zr)[64], float (&zi)[64]) {
#pragma unroll
  for (int s = 1; s <= 6; ++s) {
    const int half = 1 << (s - 1);
#pragma unroll
    for (int i = 0; i < 64; i += (1 << s)) {
#pragma unroll
      for (int j = 0; j < half; ++j) {
        const int tw = j << (7 - s);
        const float wr = DTAB.c[tw];
        const float wi = INV ? DTAB.s[tw] : -DTAB.s[tw];
        const int i0 = i + j, i1 = i0 + half;
        const float xr = zr[i1], xi = zi[i1];
        const float vr = xr * wr - xi * wi;
        const float vi = xr * wi + xi * wr;
        const float ur = zr[i0], ui = zi[i0];
        zr[i0] = ur + vr; zi[i0] = ui + vi;
        zr[i1] = ur - vr; zi[i1] = ui - vi;
      }
    }
  }
}

// ---------- K1: rfft along W (packed even/odd trick), scale 1/128
__global__ __launch_bounds__(256, 1) void k_rfft_w(const float* __restrict__ x,
                                                   float2* __restrict__ S) {
  const int idx = blockIdx.x * 256 + threadIdx.x;
  const int c  = idx % CH;
  const int bh = idx / CH;
  const float* px = x + (size_t)bh * (WWW * CH) + c;
  float zr[64], zi[64];
#pragma unroll
  for (int n = 0; n < 64; ++n) {
    zr[rev6(n)] = px[(size_t)(2 * n) * CH];
    zi[rev6(n)] = px[(size_t)(2 * n + 1) * CH];
  }
  fft64_reg<false>(zr, zi);
  float2* pS = S + (size_t)bh * (WF * CH) + c;
  const float sc = 1.0f / 128.0f;
#pragma unroll
  for (int k = 0; k <= 32; ++k) {
    const int m = (64 - k) & 63;
    const float ar = zr[k], ai = zi[k];
    const float br = zr[m], bi = zi[m];
    const float Er = 0.5f * (ar + br), Ei = 0.5f * (ai - bi);
    const float Or = 0.5f * (ai + bi), Oi = 0.5f * (br - ar);
    const float wr = DTAB.c[k], wi = -DTAB.s[k];
    const float Tr = Or * wr - Oi * wi;
    const float Ti = Or * wi + Oi * wr;
    pS[(size_t)k * CH] = make_float2(sc * (Er + Tr), sc * (Ei + Ti));
    if (k != 32)
      pS[(size_t)(64 - k) * CH] = make_float2(sc * (Er - Tr), sc * (Ti - Ei));
  }
}

// ---------- weight pre-pack: combined complex-as-real 192x192 per (block, layer),
// bf16, stored in MFMA-fragment order [n][layer][ki][ni][lane][j]
__global__ __launch_bounds__(256) void k_pack(const float* __restrict__ w1,
                                              const float* __restrict__ w2,
                                              ushort_t* __restrict__ Bpk) {
  const int t = blockIdx.x * 256 + threadIdx.x;
  const int nl   = t / 36864;
  const int rem  = t % 36864;
  const int ki   = rem / 6144;
  const int rem2 = rem % 6144;
  const int ni   = rem2 / 512;
  const int rem3 = rem2 % 512;
  const int lane = rem3 >> 3, j = rem3 & 7;
  const int n = nl >> 1, layer = nl & 1;
  const int k   = ki * 32 + (lane >> 4) * 8 + j;
  const int col = ni * 16 + (lane & 15);
  const int kk = (k < 96) ? k : k - 96;
  const int cc = (col < 96) ? col : col - 96;
  const int f  = ((k < 96) != (col < 96)) ? 1 : 0;
  const float sgn = (k >= 96 && col < 96) ? -1.f : 1.f;
  const float* w = layer ? w2 : w1;
  const float val = sgn * w[((size_t)(f * 8 + n) * 96 + kk) * 96 + cc];
  Bpk[t] = rnbf(val);
}

// ---------- K2 (fused): H-FFT(fwd) -> block MLP (MFMA) -> H-FFT(inv), one WG per (b,wf,n)
__global__ __launch_bounds__(256, 1) void k_fused(float2* __restrict__ S,
                                                  const ushort_t* __restrict__ Bpk,
                                                  const float* __restrict__ b1,
                                                  const float* __restrict__ b2) {
  __shared__ __attribute__((aligned(16))) float lsr[128 * LDST];  // re plane; reused as o1 (ushort[128][200])
  __shared__ __attribute__((aligned(16))) float lsi[128 * LDST];  // im plane
  const int tid = threadIdx.x;
  const int wg = blockIdx.x;
  const int n = wg & 7;
  const int rest = wg >> 3;
  const int wf = rest % WF;
  const int b  = rest / WF;
  float2* gbase = S + ((size_t)(b * 128) * WF + wf) * CH + n * BC;
  const size_t hs = (size_t)WF * CH;

  // ----- load 128 h x 96 c (float4 = 2 complex), bit-reversed rows
#pragma unroll
  for (int i = 0; i < 24; ++i) {
    const int q = tid + i * 256;            // 0..6143
    const int h = q / 48;
    const int cp = q - h * 48;              // pair index 0..47
    const float4 v = *(const float4*)(gbase + (size_t)h * hs + 2 * cp);
    const int hb = (int)(__brev((unsigned)h) >> 25);
    *(float2*)&lsr[hb * LDST + 2 * cp] = make_float2(v.x, v.z);
    *(float2*)&lsi[hb * LDST + 2 * cp] = make_float2(v.y, v.w);
  }

  const int ct = tid & 31, bt = tid >> 5;
  auto fftpass = [&](bool inv) {
    for (int s = 1; s <= 7; ++s) {
      __syncthreads();
      const int half = 1 << (s - 1);
#pragma unroll
      for (int cth = 0; cth < 3; ++cth) {
#pragma unroll
        for (int j = 0; j < 8; ++j) {
          const int bf = bt * 8 + j;
          const int jj = bf & (half - 1);
          const int i0 = ((bf >> (s - 1)) << s) + jj;
          const int i1 = i0 + half;
          const int tw = jj << (7 - s);
          const float wr = DTAB.c[tw];
          const float wi = inv ? DTAB.s[tw] : -DTAB.s[tw];
          const int c = cth * 32 + ct;
          const int a0 = i0 * LDST + c, a1a = i1 * LDST + c;
          const float xr = lsr[a1a], xi = lsi[a1a];
          const float vr = xr * wr - xi * wi;
          const float vi = xr * wi + xi * wr;
          const float ur = lsr[a0], ui = lsi[a0];
          lsr[a0] = ur + vr;  lsi[a0] = ui + vi;
          lsr[a1a] = ur - vr; lsi[a1a] = ui - vi;
        }
      }
    }
    __syncthreads();
  };

  fftpass(false);   // forward H-FFT (natural order now in LDS)

  // ----- MLP: wave owns 32 rows (2 tiles of 16); combined K=N=192 complex-as-real GEMMs
  const int l = tid & 63, wid = tid >> 6;
  const int lr_ = l & 15, lg = l >> 4;

  // A1 fragments from LDS f32 -> bf16
  U8 a1[2][6];
#pragma unroll
  for (int rt = 0; rt < 2; ++rt) {
    const int row = wid * 32 + rt * 16 + lr_;
#pragma unroll
    for (int ki = 0; ki < 6; ++ki) {
      const float* src = (ki < 3) ? &lsr[row * LDST + ki * 32 + lg * 8]
                                  : &lsi[row * LDST + (ki - 3) * 32 + lg * 8];
      const float4 f0 = *(const float4*)src;
      const float4 f1 = *(const float4*)(src + 4);
      a1[rt][ki].u[0] = rnbf(f0.x); a1[rt][ki].u[1] = rnbf(f0.y);
      a1[rt][ki].u[2] = rnbf(f0.z); a1[rt][ki].u[3] = rnbf(f0.w);
      a1[rt][ki].u[4] = rnbf(f1.x); a1[rt][ki].u[5] = rnbf(f1.y);
      a1[rt][ki].u[6] = rnbf(f1.z); a1[rt][ki].u[7] = rnbf(f1.w);
    }
  }

  f32x4 acc[2][12];
#pragma unroll
  for (int ni = 0; ni < 12; ++ni) {
    const int col = ni * 16 + lr_;
    const float bv = (col < 96) ? b1[n * 96 + col] : b1[768 + n * 96 + col - 96];
    acc[0][ni] = (f32x4){bv, bv, bv, bv};
    acc[1][ni] = acc[0][ni];
  }
  const uint4* bq1 = (const uint4*)(Bpk + (size_t)(n * 2 + 0) * 36864) + l;
#pragma unroll
  for (int ni = 0; ni < 12; ++ni)
#pragma unroll
    for (int ki = 0; ki < 6; ++ki) {
      U8 bb; bb.q = bq1[(ki * 12 + ni) * 64];
      acc[0][ni] = __builtin_amdgcn_mfma_f32_16x16x32_bf16(a1[0][ki].v, bb.v, acc[0][ni], 0, 0, 0);
      acc[1][ni] = __builtin_amdgcn_mfma_f32_16x16x32_bf16(a1[1][ki].v, bb.v, acc[1][ni], 0, 0, 0);
    }

  // relu -> bf16 -> o1 tile overlaid on lsr (rows are wave-local; same-wave DS ordering)
  ushort_t* o1 = (ushort_t*)lsr;
#pragma unroll
  for (int rt = 0; rt < 2; ++rt)
#pragma unroll
    for (int ni = 0; ni < 12; ++ni) {
      const int col = ni * 16 + lr_;
#pragma unroll
      for (int r = 0; r < 4; ++r) {
        const int row = wid * 32 + rt * 16 + lg * 4 + r;
        o1[row * 200 + col] = rnbf(fmaxf(acc[rt][ni][r], 0.f));
      }
    }

  // A2 fragments (wave-local rows of o1)
  U8 a2[2][6];
#pragma unroll
  for (int rt = 0; rt < 2; ++rt) {
    const int row = wid * 32 + rt * 16 + lr_;
#pragma unroll
    for (int ki = 0; ki < 6; ++ki)
      a2[rt][ki].q = *(const uint4*)&o1[row * 200 + ki * 32 + lg * 8];
  }
  __syncthreads();   // all lr/o1 reads done before f32 result scatter below

#pragma unroll
  for (int ni = 0; ni < 12; ++ni) {
    const int col = ni * 16 + lr_;
    const float bv = (col < 96) ? b2[n * 96 + col] : b2[768 + n * 96 + col - 96];
    acc[0][ni] = (f32x4){bv, bv, bv, bv};
    acc[1][ni] = acc[0][ni];
  }
  const uint4* bq2 = (const uint4*)(Bpk + (size_t)(n * 2 + 1) * 36864) + l;
#pragma unroll
  for (int ni = 0; ni < 12; ++ni)
#pragma unroll
    for (int ki = 0; ki < 6; ++ki) {
      U8 bb; bb.q = bq2[(ki * 12 + ni) * 64];
      acc[0][ni] = __builtin_amdgcn_mfma_f32_16x16x32_bf16(a2[0][ki].v, bb.v, acc[0][ni], 0, 0, 0);
      acc[1][ni] = __builtin_amdgcn_mfma_f32_16x16x32_bf16(a2[1][ki].v, bb.v, acc[1][ni], 0, 0, 0);
    }

  // softshrink -> scatter f32 into bit-reversed rows (input order for inverse DIT)
#pragma unroll
  for (int rt = 0; rt < 2; ++rt)
#pragma unroll
    for (int ni = 0; ni < 12; ++ni) {
      const int col = ni * 16 + lr_;
      const int c    = (col < 96) ? col : col - 96;
      float* plane = (col < 96) ? lsr : lsi;
#pragma unroll
      for (int r = 0; r < 4; ++r) {
        const int p = wid * 32 + rt * 16 + lg * 4 + r;
        const int tr = (int)(__brev((unsigned)p) >> 25);
        float v = acc[rt][ni][r];
        v = v > LAMBD_ ? v - LAMBD_ : (v < -LAMBD_ ? v + LAMBD_ : 0.f);
        plane[tr * LDST + c] = v;
      }
    }

  fftpass(true);    // inverse H-FFT (unnormalized; 1/128 applied in k_irfft_w)

  // ----- store back
#pragma unroll
  for (int i = 0; i < 24; ++i) {
    const int q = tid + i * 256;
    const int h = q / 48;
    const int cp = q - h * 48;
    const float2 r2 = *(const float2*)&lsr[h * LDST + 2 * cp];
    const float2 i2 = *(const float2*)&lsi[h * LDST + 2 * cp];
    *(float4*)(gbase + (size_t)h * hs + 2 * cp) = make_float4(r2.x, i2.x, r2.y, i2.y);
  }
}

// ---------- K3: inverse rfft along W + residual
__global__ __launch_bounds__(256, 1) void k_irfft_w(const float2* __restrict__ S,
                                                    const float* __restrict__ x,
                                                    float* __restrict__ out) {
  const int idx = blockIdx.x * 256 + threadIdx.x;
  const int c  = idx % CH;
  const int bh = idx / CH;
  const float2* pS = S + (size_t)bh * (WF * CH) + c;
  float zr[64], zi[64];
#pragma unroll
  for (int k = 0; k <= 32; ++k) {
    float2 Yk = pS[(size_t)k * CH];
    float2 Ym = pS[(size_t)(64 - k) * CH];
    if (k == 0) { Yk.y = 0.f; Ym.y = 0.f; }
    const float er = Yk.x + Ym.x, ei = Yk.y - Ym.y;
    const float dr = Yk.x - Ym.x, di = Yk.y + Ym.y;
    const float wr = DTAB.c[k], wi = DTAB.s[k];
    const float o_r = dr * wr - di * wi;
    const float o_i = dr * wi + di * wr;
    zr[rev6(k)] = er - o_i;  zi[rev6(k)] = ei + o_r;
    if (k > 0 && k < 32) {
      zr[rev6(64 - k)] = er + o_i;  zi[rev6(64 - k)] = o_r - ei;
    }
  }
  fft64_reg<true>(zr, zi);
  const float sc = 1.0f / 128.0f;
  const float* px = x + (size_t)bh * (WWW * CH) + c;
  float* po = out + (size_t)bh * (WWW * CH) + c;
#pragma unroll
  for (int n = 0; n < 64; ++n) {
    po[(size_t)(2 * n) * CH]     = fmaf(zr[n], sc, px[(size_t)(2 * n) * CH]);
    po[(size_t)(2 * n + 1) * CH] = fmaf(zi[n], sc, px[(size_t)(2 * n + 1) * CH]);
  }
}

extern "C" void kernel_launch(void* const* d_in, const int* in_sizes, int n_in,
                              void* d_out, int out_size, void* d_ws, size_t ws_size,
                              hipStream_t stream) {
  (void)in_sizes; (void)n_in; (void)out_size; (void)ws_size;
  const float* x  = (const float*)d_in[0];
  const float* w1 = (const float*)d_in[1];
  const float* b1 = (const float*)d_in[2];
  const float* w2 = (const float*)d_in[3];
  const float* b2 = (const float*)d_in[4];
  float* out = (float*)d_out;
  float2* S  = (float2*)d_ws;                           // spectrum, 204.5 MB
  ushort_t* Bpk = (ushort_t*)((char*)d_ws + SOFF);      // packed bf16 weights, 1.13 MB

  k_pack<<<dim3(2304), dim3(256), 0, stream>>>(w1, w2, Bpk);
  k_rfft_w<<<dim3(1536), dim3(256), 0, stream>>>(x, S);
  k_fused<<<dim3(4 * WF * 8), dim3(256), 0, stream>>>(S, Bpk, b1, b2);
  k_irfft_w<<<dim3(1536), dim3(256), 0, stream>>>(S, x, out);
}